// Round 6
// baseline (516.645 us; speedup 1.0000x reference)
//
#include <hip/hip_runtime.h>

typedef unsigned short ushort_t;
typedef unsigned int   uint_t;

using bf16x8 = __attribute__((ext_vector_type(8))) short;
using f32x16 = __attribute__((ext_vector_type(16))) float;

#define BATCH 16
#define CIN   64
#define COUT  64
#define LSIG  16384
#define KW    128
#define LOUT  (LSIG - KW + 1)   /* 16257 */

#define NTILE 512                /* output positions per block */
#define ROWS  640                /* NTILE + 127 halo, rounded to 16 */

__device__ __forceinline__ ushort_t f2bf(float f) {
  union { float f; uint_t u; } v; v.f = f;
  uint_t r = v.u + 0x7fffu + ((v.u >> 16) & 1u);   // RNE, matches jnp f32->bf16
  return (ushort_t)(r >> 16);
}

// ---------------- pass 1: max|w| ----------------
__global__ void k_absmax(const float* __restrict__ w, uint_t* __restrict__ amax, int n) {
  int idx = blockIdx.x * blockDim.x + threadIdx.x;
  int stride = gridDim.x * blockDim.x;
  float m = 0.f;
  for (int i = idx; i < n; i += stride) m = fmaxf(m, fabsf(w[i]));
  for (int off = 32; off > 0; off >>= 1) m = fmaxf(m, __shfl_down(m, off, 64));
  if ((threadIdx.x & 63) == 0) atomicMax(amax, __float_as_uint(m)); // positive floats: uint order == float order
}

// ---------------- pass 2: quantize + reorder weights to Wt[k][o][i] (bf16 of integer) ----------------
__global__ void k_wprep(const float* __restrict__ w, const float* __restrict__ amaxp,
                        ushort_t* __restrict__ wt) {
  const float scale = amaxp[0] / 127.0f;
  const int o = blockIdx.x, i = blockIdx.y, k = threadIdx.x;
  const float q = rintf(w[((size_t)o * CIN + i) * KW + k] / scale); // integer in [-127,127], exact in bf16
  wt[((size_t)k * COUT + o) * CIN + i] = f2bf(q);
}

// ---------------- pass 3: signal -> sigT[b][n][i] bf16, i-block XOR-swizzled by (n&7) ----------------
__global__ void k_sprep(const float* __restrict__ sig, ushort_t* __restrict__ sigT) {
  __shared__ float tile[64][65];
  const int b = blockIdx.y;
  const int n0 = blockIdx.x * 64;
  const int t = threadIdx.x;
  {
    const int i = t >> 2, q = t & 3;
    const float4* src = (const float4*)(sig + ((size_t)(b * CIN + i)) * LSIG + n0 + q * 16);
    float4 v0 = src[0], v1 = src[1], v2 = src[2], v3 = src[3];
    float* trow = &tile[i][q * 16];
    trow[0]=v0.x; trow[1]=v0.y; trow[2]=v0.z;  trow[3]=v0.w;
    trow[4]=v1.x; trow[5]=v1.y; trow[6]=v1.z;  trow[7]=v1.w;
    trow[8]=v2.x; trow[9]=v2.y; trow[10]=v2.z; trow[11]=v2.w;
    trow[12]=v3.x; trow[13]=v3.y; trow[14]=v3.z; trow[15]=v3.w;
  }
  __syncthreads();
  const int nl = t & 63, cg = t >> 6;
  const int n = n0 + nl;
  uint_t wds[8];
#pragma unroll
  for (int p = 0; p < 8; ++p) {
    const int c0 = cg * 16 + 2 * p;
    const int c1 = c0 + 1;
    const int ia = (((c0 >> 3) ^ (n & 7)) << 3) | (c0 & 7);
    const int ib = (((c1 >> 3) ^ (n & 7)) << 3) | (c1 & 7);
    wds[p] = (uint_t)f2bf(tile[ia][nl]) | ((uint_t)f2bf(tile[ib][nl]) << 16);
  }
  uint4* dst = (uint4*)(sigT + ((size_t)b * LSIG + n) * CIN + cg * 16);
  dst[0] = make_uint4(wds[0], wds[1], wds[2], wds[3]);
  dst[1] = make_uint4(wds[4], wds[5], wds[6], wds[7]);
}

// ---------------- pass 4: the conv (implicit GEMM, 32x32x16 MFMA) ----------------
// block: 512 threads = 8 waves; each wave owns 64 output positions x all 64 Cout.
// grid = 32 x 16 = 512 blocks = exactly 2 blocks/CU (2x80KB LDS = 160KB), 16 waves/CU
// = 4 waves/SIMD (requires <=128 regs/wave: acc 64 + A/B dbuf 32 + addr).
// A = weights (m = o, 2 frags of 32), B = signal (n = position, 2 frags of 32),
// k-dim = Cin as 4 slices of 16. Step = (tap, ks): 2 A-loads + 2 B ds_reads + 4 MFMA.
// 512 steps, software-pipelined one step ahead, no barriers after the staging sync.
#define CONV_STEP(S, AUSE, ALOAD, BUSE, BLOAD, DO_PF) do {                             \
    if (DO_PF) {                                                                       \
      const int sn_ = (S) + 1;                                                         \
      const int tp_ = sn_ >> 2, kn_ = sn_ & 3;                                         \
      _Pragma("unroll") for (int of = 0; of < 2; ++of)                                 \
        ALOAD[of] = *(const bf16x8*)(wa + tp_ * 4096 + of * 2048 + kn_ * 16);          \
      const int rb_ = rowbase + tp_;                                                   \
      _Pragma("unroll") for (int nf = 0; nf < 2; ++nf) {                               \
        const int r_ = rb_ + nf * 32;                                                  \
        BLOAD[nf] = *(const bf16x8*)((const char*)lds + r_ * 128 +                     \
                                     ((((kn_ << 1) | hi) ^ (r_ & 7)) << 4));           \
      }                                                                                \
    }                                                                                  \
    _Pragma("unroll") for (int of = 0; of < 2; ++of)                                   \
      _Pragma("unroll") for (int nf = 0; nf < 2; ++nf)                                 \
        acc[of][nf] = __builtin_amdgcn_mfma_f32_32x32x16_bf16(AUSE[of], BUSE[nf], acc[of][nf], 0, 0, 0); \
  } while (0)

__global__ __launch_bounds__(512, 4) void k_conv(
    const ushort_t* __restrict__ sigT, const ushort_t* __restrict__ wt,
    const float* __restrict__ amaxp, const float* __restrict__ bias,
    float* __restrict__ out)
{
  __shared__ __align__(16) ushort_t lds[ROWS * CIN];   // 80 KB
  const int b  = blockIdx.y;
  const int n0 = blockIdx.x * NTILE;
  const int t  = threadIdx.x;
  const int wv = t >> 6;
  const int lane = t & 63;
  const int l31 = lane & 31, hi = lane >> 5;

  // stage 640 rows x 128B = one contiguous 80KB span of sigT (clamped at buffer end;
  // overrun rows only feed store-masked outputs)
  {
    const uint4* srcall = (const uint4*)sigT;
    const size_t base = ((size_t)b * LSIG + n0) * 8;       // 8 uint4 per 128B row
    const size_t lim  = (size_t)BATCH * LSIG * 8;
    uint4* dst = (uint4*)lds;
    for (int c = t; c < ROWS * 8; c += 512) {
      size_t g = base + c;
      if (g >= lim) g = lim - 1;
      dst[c] = srcall[g];
    }
  }
  __syncthreads();

  f32x16 acc[2][2];
#pragma unroll
  for (int i = 0; i < 2; ++i)
#pragma unroll
    for (int j = 0; j < 2; ++j)
#pragma unroll
      for (int r = 0; r < 16; ++r) acc[i][j][r] = 0.f;

  // A: lane holds o = of*32 + l31, i = ks*16 + hi*8 + j  (16B contiguous in wt)
  const ushort_t* wa = wt + l31 * CIN + hi * 8;
  const int rowbase = wv * 64 + l31;   // wave owns positions [wv*64, wv*64+64)

  bf16x8 A0[2], A1[2], B0[2], B1[2];
#pragma unroll
  for (int of = 0; of < 2; ++of) A0[of] = *(const bf16x8*)(wa + of * 2048);
  {
    // prologue: B for step 0 (tap 0, ks 0)
#pragma unroll
    for (int nf = 0; nf < 2; ++nf) {
      const int r_ = rowbase + nf * 32;
      B0[nf] = *(const bf16x8*)((const char*)lds + r_ * 128 + (((hi) ^ (r_ & 7)) << 4));
    }
  }

  for (int s = 0; s < 512; s += 2) {
    CONV_STEP(s,     A0, A1, B0, B1, 1);
    CONV_STEP(s + 1, A1, A0, B1, B0, (s + 2 < 512));
  }

  const float sc = amaxp[0] / 127.0f;
#pragma unroll
  for (int of = 0; of < 2; ++of) {
#pragma unroll
    for (int nf = 0; nf < 2; ++nf) {
      const int n = n0 + wv * 64 + nf * 32 + l31;
      if (n < LOUT) {
#pragma unroll
        for (int r = 0; r < 16; ++r) {
          // D: col = lane&31 (= n), row o = of*32 + 4*hi + (r&3) + 8*(r>>2)  [m74/m101 layout]
          const int o = of * 32 + 4 * hi + (r & 3) + 8 * (r >> 2);
          out[((size_t)b * COUT + o) * LOUT + n] = acc[of][nf][r] * sc + bias[o];
        }
      }
    }
  }
}

extern "C" void kernel_launch(void* const* d_in, const int* in_sizes, int n_in,
                              void* d_out, int out_size, void* d_ws, size_t ws_size,
                              hipStream_t stream) {
  const float* sig  = (const float*)d_in[0];
  const float* w    = (const float*)d_in[1];
  const float* bias = (const float*)d_in[2];
  float* out = (float*)d_out;

  // workspace layout: [0,4): amax bits | [4096, 4096+1MB): Wt | [2MB, 2MB+32MB): sigT (+16KB read slack)
  uint_t*   amax = (uint_t*)d_ws;
  ushort_t* wt   = (ushort_t*)((char*)d_ws + 4096);
  ushort_t* sigT = (ushort_t*)((char*)d_ws + (size_t)(2u << 20));

  hipMemsetAsync(d_ws, 0, 4, stream);
  hipLaunchKernelGGL(k_absmax, dim3(256), dim3(256), 0, stream, w, amax, COUT * CIN * KW);
  hipLaunchKernelGGL(k_wprep, dim3(COUT, CIN), dim3(KW), 0, stream, w, (const float*)amax, wt);
  hipLaunchKernelGGL(k_sprep, dim3(LSIG / 64, BATCH), dim3(256), 0, stream, sig, sigT);
  hipLaunchKernelGGL(k_conv, dim3((LOUT + NTILE - 1) / NTILE, BATCH), dim3(512), 0, stream,
                     sigT, wt, (const float*)amax, bias, out);
}

// Round 7
// 295.961 us; speedup vs baseline: 1.7457x; 1.7457x over previous
//
#include <hip/hip_runtime.h>

typedef unsigned short ushort_t;
typedef unsigned int   uint_t;

using bf16x8 = __attribute__((ext_vector_type(8))) short;
using f32x16 = __attribute__((ext_vector_type(16))) float;

#define BATCH 16
#define CIN   64
#define COUT  64
#define LSIG  16384
#define KW    128
#define LOUT  (LSIG - KW + 1)   /* 16257 */

#define NTILE 512                /* output positions per block */
#define ROWS  640                /* NTILE + 127 halo, rounded to 16 */

__device__ __forceinline__ ushort_t f2bf(float f) {
  union { float f; uint_t u; } v; v.f = f;
  uint_t r = v.u + 0x7fffu + ((v.u >> 16) & 1u);   // RNE, matches jnp f32->bf16
  return (ushort_t)(r >> 16);
}

// ---------------- pass 1: max|w| ----------------
__global__ void k_absmax(const float* __restrict__ w, uint_t* __restrict__ amax, int n) {
  int idx = blockIdx.x * blockDim.x + threadIdx.x;
  int stride = gridDim.x * blockDim.x;
  float m = 0.f;
  for (int i = idx; i < n; i += stride) m = fmaxf(m, fabsf(w[i]));
  for (int off = 32; off > 0; off >>= 1) m = fmaxf(m, __shfl_down(m, off, 64));
  if ((threadIdx.x & 63) == 0) atomicMax(amax, __float_as_uint(m)); // positive floats: uint order == float order
}

// ---------------- pass 2: quantize + reorder weights to Wt[k][o][i] (bf16 of integer) ----------------
__global__ void k_wprep(const float* __restrict__ w, const float* __restrict__ amaxp,
                        ushort_t* __restrict__ wt) {
  const float scale = amaxp[0] / 127.0f;
  const int o = blockIdx.x, i = blockIdx.y, k = threadIdx.x;
  const float q = rintf(w[((size_t)o * CIN + i) * KW + k] / scale); // integer in [-127,127], exact in bf16
  wt[((size_t)k * COUT + o) * CIN + i] = f2bf(q);
}

// ---------------- pass 3: signal -> sigT[b][n][i] bf16, i-block XOR-swizzled by (n&7) ----------------
__global__ void k_sprep(const float* __restrict__ sig, ushort_t* __restrict__ sigT) {
  __shared__ float tile[64][65];
  const int b = blockIdx.y;
  const int n0 = blockIdx.x * 64;
  const int t = threadIdx.x;
  {
    const int i = t >> 2, q = t & 3;
    const float4* src = (const float4*)(sig + ((size_t)(b * CIN + i)) * LSIG + n0 + q * 16);
    float4 v0 = src[0], v1 = src[1], v2 = src[2], v3 = src[3];
    float* trow = &tile[i][q * 16];
    trow[0]=v0.x; trow[1]=v0.y; trow[2]=v0.z;  trow[3]=v0.w;
    trow[4]=v1.x; trow[5]=v1.y; trow[6]=v1.z;  trow[7]=v1.w;
    trow[8]=v2.x; trow[9]=v2.y; trow[10]=v2.z; trow[11]=v2.w;
    trow[12]=v3.x; trow[13]=v3.y; trow[14]=v3.z; trow[15]=v3.w;
  }
  __syncthreads();
  const int nl = t & 63, cg = t >> 6;
  const int n = n0 + nl;
  uint_t wds[8];
#pragma unroll
  for (int p = 0; p < 8; ++p) {
    const int c0 = cg * 16 + 2 * p;
    const int c1 = c0 + 1;
    const int ia = (((c0 >> 3) ^ (n & 7)) << 3) | (c0 & 7);
    const int ib = (((c1 >> 3) ^ (n & 7)) << 3) | (c1 & 7);
    wds[p] = (uint_t)f2bf(tile[ia][nl]) | ((uint_t)f2bf(tile[ib][nl]) << 16);
  }
  uint4* dst = (uint4*)(sigT + ((size_t)b * LSIG + n) * CIN + cg * 16);
  dst[0] = make_uint4(wds[0], wds[1], wds[2], wds[3]);
  dst[1] = make_uint4(wds[4], wds[5], wds[6], wds[7]);
}

// ---------------- pass 4: the conv (implicit GEMM, 32x32x16 MFMA, depth-2 pipeline) ----------------
// block: 256 threads = 4 waves; each wave owns 128 output positions x all 64 Cout.
// grid = 32 x 16 = 512 blocks = exactly 2 blocks/CU (2x80KB LDS = 160KB), 8 waves/CU.
// A = weights (m = o, 2 frags of 32), B = signal (n = position, 4 frags of 32),
// k-dim = Cin as 4 slices of 16. Step = (tap, ks): 2 A-loads + 4 B ds_reads + 8 MFMA.
// 512 steps; 4 rotating register buffer sets, prefetch distance 2 steps (~620 cyc of
// MFMA cover > worst-case L2 latency), so waits are counted, never immediate.
#define CONV_STEP(S, U, L, DO_PF) do {                                                 \
    if (DO_PF) {                                                                       \
      const int sn_ = (S) + 2;                                                         \
      const int tp_ = sn_ >> 2, kn_ = sn_ & 3;                                         \
      _Pragma("unroll") for (int of = 0; of < 2; ++of)                                 \
        Abuf[L][of] = *(const bf16x8*)(wa + tp_ * 4096 + of * 2048 + kn_ * 16);        \
      const int rb_ = rowbase + tp_;                                                   \
      _Pragma("unroll") for (int nf = 0; nf < 4; ++nf) {                               \
        const int r_ = rb_ + nf * 32;                                                  \
        Bbuf[L][nf] = *(const bf16x8*)((const char*)lds + r_ * 128 +                   \
                                       ((((kn_ << 1) | hi) ^ (r_ & 7)) << 4));         \
      }                                                                                \
    }                                                                                  \
    _Pragma("unroll") for (int of = 0; of < 2; ++of)                                   \
      _Pragma("unroll") for (int nf = 0; nf < 4; ++nf)                                 \
        acc[of][nf] = __builtin_amdgcn_mfma_f32_32x32x16_bf16(Abuf[U][of], Bbuf[U][nf], acc[of][nf], 0, 0, 0); \
  } while (0)

__global__ __launch_bounds__(256, 2) void k_conv(
    const ushort_t* __restrict__ sigT, const ushort_t* __restrict__ wt,
    const float* __restrict__ amaxp, const float* __restrict__ bias,
    float* __restrict__ out)
{
  __shared__ __align__(16) ushort_t lds[ROWS * CIN];   // 80 KB
  const int b  = blockIdx.y;
  const int n0 = blockIdx.x * NTILE;
  const int t  = threadIdx.x;
  const int wv = t >> 6;
  const int lane = t & 63;
  const int l31 = lane & 31, hi = lane >> 5;

  // stage 640 rows x 128B = one contiguous 80KB span of sigT (clamped at buffer end;
  // overrun rows only feed store-masked outputs)
  {
    const uint4* srcall = (const uint4*)sigT;
    const size_t base = ((size_t)b * LSIG + n0) * 8;       // 8 uint4 per 128B row
    const size_t lim  = (size_t)BATCH * LSIG * 8;
    uint4* dst = (uint4*)lds;
    for (int c = t; c < ROWS * 8; c += 256) {
      size_t g = base + c;
      if (g >= lim) g = lim - 1;
      dst[c] = srcall[g];
    }
  }
  __syncthreads();

  f32x16 acc[2][4];
#pragma unroll
  for (int i = 0; i < 2; ++i)
#pragma unroll
    for (int j = 0; j < 4; ++j)
#pragma unroll
      for (int r = 0; r < 16; ++r) acc[i][j][r] = 0.f;

  // A: lane holds o = of*32 + l31, i = ks*16 + hi*8 + j  (16B contiguous in wt)
  const ushort_t* wa = wt + l31 * CIN + hi * 8;
  const int rowbase = wv * 128 + l31;

  bf16x8 Abuf[4][2], Bbuf[4][4];
  // prologue: step 0 (tap 0, ks 0) -> buf 0; step 1 (tap 0, ks 1) -> buf 1
#pragma unroll
  for (int of = 0; of < 2; ++of) {
    Abuf[0][of] = *(const bf16x8*)(wa + of * 2048);
    Abuf[1][of] = *(const bf16x8*)(wa + of * 2048 + 16);
  }
#pragma unroll
  for (int nf = 0; nf < 4; ++nf) {
    const int r_ = rowbase + nf * 32;
    Bbuf[0][nf] = *(const bf16x8*)((const char*)lds + r_ * 128 + (((hi)     ^ (r_ & 7)) << 4));
    Bbuf[1][nf] = *(const bf16x8*)((const char*)lds + r_ * 128 + (((2 | hi) ^ (r_ & 7)) << 4));
  }

  for (int s = 0; s < 512; s += 4) {
    CONV_STEP(s + 0, 0, 2, 1);
    CONV_STEP(s + 1, 1, 3, 1);
    CONV_STEP(s + 2, 2, 0, (s + 4 < 512));
    CONV_STEP(s + 3, 3, 1, (s + 5 < 512));
  }

  const float sc = amaxp[0] / 127.0f;
#pragma unroll
  for (int of = 0; of < 2; ++of) {
#pragma unroll
    for (int nf = 0; nf < 4; ++nf) {
      const int n = n0 + wv * 128 + nf * 32 + l31;
      if (n < LOUT) {
#pragma unroll
        for (int r = 0; r < 16; ++r) {
          // D: col = lane&31 (= n), row o = of*32 + 4*hi + (r&3) + 8*(r>>2)  [m74/m101 layout]
          const int o = of * 32 + 4 * hi + (r & 3) + 8 * (r >> 2);
          out[((size_t)b * COUT + o) * LOUT + n] = acc[of][nf][r] * sc + bias[o];
        }
      }
    }
  }
}

extern "C" void kernel_launch(void* const* d_in, const int* in_sizes, int n_in,
                              void* d_out, int out_size, void* d_ws, size_t ws_size,
                              hipStream_t stream) {
  const float* sig  = (const float*)d_in[0];
  const float* w    = (const float*)d_in[1];
  const float* bias = (const float*)d_in[2];
  float* out = (float*)d_out;

  // workspace layout: [0,4): amax bits | [4096, 4096+1MB): Wt | [2MB, 2MB+32MB): sigT (+16KB read slack)
  uint_t*   amax = (uint_t*)d_ws;
  ushort_t* wt   = (ushort_t*)((char*)d_ws + 4096);
  ushort_t* sigT = (ushort_t*)((char*)d_ws + (size_t)(2u << 20));

  hipMemsetAsync(d_ws, 0, 4, stream);
  hipLaunchKernelGGL(k_absmax, dim3(256), dim3(256), 0, stream, w, amax, COUT * CIN * KW);
  hipLaunchKernelGGL(k_wprep, dim3(COUT, CIN), dim3(KW), 0, stream, w, (const float*)amax, wt);
  hipLaunchKernelGGL(k_sprep, dim3(LSIG / 64, BATCH), dim3(256), 0, stream, sig, sigT);
  hipLaunchKernelGGL(k_conv, dim3((LOUT + NTILE - 1) / NTILE, BATCH), dim3(256), 0, stream,
                     sigT, wt, (const float*)amax, bias, out);
}

// Round 8
// 295.904 us; speedup vs baseline: 1.7460x; 1.0002x over previous
//
#include <hip/hip_runtime.h>

typedef unsigned short ushort_t;
typedef unsigned int   uint_t;

using bf16x8 = __attribute__((ext_vector_type(8))) short;
using f32x16 = __attribute__((ext_vector_type(16))) float;

#define BATCH 16
#define CIN   64
#define COUT  64
#define LSIG  16384
#define KW    128
#define LOUT  (LSIG - KW + 1)   /* 16257 */

#define NTILE 512                /* output positions per block */
#define ROWS  640                /* NTILE + 127 halo, rounded to 16 */

__device__ __forceinline__ ushort_t f2bf(float f) {
  union { float f; uint_t u; } v; v.f = f;
  uint_t r = v.u + 0x7fffu + ((v.u >> 16) & 1u);   // RNE, matches jnp f32->bf16
  return (ushort_t)(r >> 16);
}

// ---------------- pass 1: max|w| ----------------
__global__ void k_absmax(const float* __restrict__ w, uint_t* __restrict__ amax, int n) {
  int idx = blockIdx.x * blockDim.x + threadIdx.x;
  int stride = gridDim.x * blockDim.x;
  float m = 0.f;
  for (int i = idx; i < n; i += stride) m = fmaxf(m, fabsf(w[i]));
  for (int off = 32; off > 0; off >>= 1) m = fmaxf(m, __shfl_down(m, off, 64));
  if ((threadIdx.x & 63) == 0) atomicMax(amax, __float_as_uint(m)); // positive floats: uint order == float order
}

// ---------------- pass 2: quantize + reorder weights to Wt[k][o][i] (bf16 of integer) ----------------
__global__ void k_wprep(const float* __restrict__ w, const float* __restrict__ amaxp,
                        ushort_t* __restrict__ wt) {
  const float scale = amaxp[0] / 127.0f;
  const int o = blockIdx.x, i = blockIdx.y, k = threadIdx.x;
  const float q = rintf(w[((size_t)o * CIN + i) * KW + k] / scale); // integer in [-127,127], exact in bf16
  wt[((size_t)k * COUT + o) * CIN + i] = f2bf(q);
}

// ---------------- pass 3: signal -> sigT[b][n][i] bf16, i-block XOR-swizzled by (n&7) ----------------
__global__ void k_sprep(const float* __restrict__ sig, ushort_t* __restrict__ sigT) {
  __shared__ float tile[64][65];
  const int b = blockIdx.y;
  const int n0 = blockIdx.x * 64;
  const int t = threadIdx.x;
  {
    const int i = t >> 2, q = t & 3;
    const float4* src = (const float4*)(sig + ((size_t)(b * CIN + i)) * LSIG + n0 + q * 16);
    float4 v0 = src[0], v1 = src[1], v2 = src[2], v3 = src[3];
    float* trow = &tile[i][q * 16];
    trow[0]=v0.x; trow[1]=v0.y; trow[2]=v0.z;  trow[3]=v0.w;
    trow[4]=v1.x; trow[5]=v1.y; trow[6]=v1.z;  trow[7]=v1.w;
    trow[8]=v2.x; trow[9]=v2.y; trow[10]=v2.z; trow[11]=v2.w;
    trow[12]=v3.x; trow[13]=v3.y; trow[14]=v3.z; trow[15]=v3.w;
  }
  __syncthreads();
  const int nl = t & 63, cg = t >> 6;
  const int n = n0 + nl;
  uint_t wds[8];
#pragma unroll
  for (int p = 0; p < 8; ++p) {
    const int c0 = cg * 16 + 2 * p;
    const int c1 = c0 + 1;
    const int ia = (((c0 >> 3) ^ (n & 7)) << 3) | (c0 & 7);
    const int ib = (((c1 >> 3) ^ (n & 7)) << 3) | (c1 & 7);
    wds[p] = (uint_t)f2bf(tile[ia][nl]) | ((uint_t)f2bf(tile[ib][nl]) << 16);
  }
  uint4* dst = (uint4*)(sigT + ((size_t)b * LSIG + n) * CIN + cg * 16);
  dst[0] = make_uint4(wds[0], wds[1], wds[2], wds[3]);
  dst[1] = make_uint4(wds[4], wds[5], wds[6], wds[7]);
}

// ---------------- pass 4: the conv (implicit GEMM, 32x32x16 MFMA, per-tap A hoist) ----------------
// block: 256 threads = 4 waves; each wave owns 128 output positions x all 64 Cout.
// grid = 32 x 16 = 512 blocks = exactly 2 blocks/CU (2x80KB LDS = 160KB), 8 waves/CU.
// A = weights (m = o, 2 frags of 32), B = signal (n = position, 4 frags of 32),
// k-dim = Cin as 4 slices of 16.
// Tap loop (128 taps): at tap top, issue ALL of next tap's 8 A-frag global loads,
// pinned by sched_barrier(0) so they cannot sink; then 4 pure-LDS ks-steps
// (4 ds_read_b128 + 8 MFMA each, B pipelined one step ahead). One vmcnt wait per
// 32 MFMAs instead of per 8.
#define KS_STEP(T, KS, A, BUSE, BLOAD, PFT, PFKS) do {                                 \
    { const int rbp_ = rowbase + (PFT);                                                \
      _Pragma("unroll") for (int nf = 0; nf < 4; ++nf) {                               \
        const int r_ = rbp_ + nf * 32;                                                 \
        BLOAD[nf] = *(const bf16x8*)((const char*)lds + r_ * 128 +                     \
                                     ((((PFKS) * 2 + hi) ^ (r_ & 7)) << 4));           \
      } }                                                                              \
    _Pragma("unroll") for (int of = 0; of < 2; ++of)                                   \
      _Pragma("unroll") for (int nf = 0; nf < 4; ++nf)                                 \
        acc[of][nf] = __builtin_amdgcn_mfma_f32_32x32x16_bf16(A[of * 4 + (KS)], BUSE[nf], acc[of][nf], 0, 0, 0); \
  } while (0)

#define TAP_BODY(T, ACUR, ANXT, DO_PF) do {                                            \
    if (DO_PF) {                                                                       \
      const ushort_t* pa_ = wa + (size_t)((T) + 1) * 4096;                             \
      _Pragma("unroll") for (int of = 0; of < 2; ++of)                                 \
        _Pragma("unroll") for (int ks = 0; ks < 4; ++ks)                               \
          ANXT[of * 4 + ks] = *(const bf16x8*)(pa_ + of * 2048 + ks * 16);             \
    }                                                                                  \
    __builtin_amdgcn_sched_barrier(0);                                                 \
    KS_STEP(T, 0, ACUR, B0, B1, (T), 1);                                               \
    KS_STEP(T, 1, ACUR, B1, B0, (T), 2);                                               \
    KS_STEP(T, 2, ACUR, B0, B1, (T), 3);                                               \
    KS_STEP(T, 3, ACUR, B1, B0, (T) + 1, 0);                                           \
  } while (0)

__global__ __launch_bounds__(256, 2) void k_conv(
    const ushort_t* __restrict__ sigT, const ushort_t* __restrict__ wt,
    const float* __restrict__ amaxp, const float* __restrict__ bias,
    float* __restrict__ out)
{
  __shared__ __align__(16) ushort_t lds[ROWS * CIN];   // 80 KB
  const int b  = blockIdx.y;
  const int n0 = blockIdx.x * NTILE;
  const int t  = threadIdx.x;
  const int wv = t >> 6;
  const int lane = t & 63;
  const int l31 = lane & 31, hi = lane >> 5;

  // stage 640 rows x 128B = one contiguous 80KB span of sigT (clamped at buffer end;
  // overrun rows only feed store-masked outputs)
  {
    const uint4* srcall = (const uint4*)sigT;
    const size_t base = ((size_t)b * LSIG + n0) * 8;       // 8 uint4 per 128B row
    const size_t lim  = (size_t)BATCH * LSIG * 8;
    uint4* dst = (uint4*)lds;
    for (int c = t; c < ROWS * 8; c += 256) {
      size_t g = base + c;
      if (g >= lim) g = lim - 1;
      dst[c] = srcall[g];
    }
  }
  __syncthreads();

  f32x16 acc[2][4];
#pragma unroll
  for (int i = 0; i < 2; ++i)
#pragma unroll
    for (int j = 0; j < 4; ++j)
#pragma unroll
      for (int r = 0; r < 16; ++r) acc[i][j][r] = 0.f;

  // A: lane holds o = of*32 + l31, i = ks*16 + hi*8 + j  (16B contiguous in wt)
  const ushort_t* wa = wt + l31 * CIN + hi * 8;
  const int rowbase = wv * 128 + l31;

  bf16x8 Aev[8], Aod[8], B0[4], B1[4];
  // prologue: full A for tap 0; B for (tap 0, ks 0)
#pragma unroll
  for (int of = 0; of < 2; ++of)
#pragma unroll
    for (int ks = 0; ks < 4; ++ks)
      Aev[of * 4 + ks] = *(const bf16x8*)(wa + of * 2048 + ks * 16);
#pragma unroll
  for (int nf = 0; nf < 4; ++nf) {
    const int r_ = rowbase + nf * 32;
    B0[nf] = *(const bf16x8*)((const char*)lds + r_ * 128 + (((hi) ^ (r_ & 7)) << 4));
  }

  for (int tp = 0; tp < KW; tp += 2) {
    TAP_BODY(tp,     Aev, Aod, 1);
    TAP_BODY(tp + 1, Aod, Aev, (tp + 2 < KW));
  }

  const float sc = amaxp[0] / 127.0f;
#pragma unroll
  for (int of = 0; of < 2; ++of) {
#pragma unroll
    for (int nf = 0; nf < 4; ++nf) {
      const int n = n0 + wv * 128 + nf * 32 + l31;
      if (n < LOUT) {
#pragma unroll
        for (int r = 0; r < 16; ++r) {
          // D: col = lane&31 (= n), row o = of*32 + 4*hi + (r&3) + 8*(r>>2)  [m74/m101 layout]
          const int o = of * 32 + 4 * hi + (r & 3) + 8 * (r >> 2);
          out[((size_t)b * COUT + o) * LOUT + n] = acc[of][nf][r] * sc + bias[o];
        }
      }
    }
  }
}

extern "C" void kernel_launch(void* const* d_in, const int* in_sizes, int n_in,
                              void* d_out, int out_size, void* d_ws, size_t ws_size,
                              hipStream_t stream) {
  const float* sig  = (const float*)d_in[0];
  const float* w    = (const float*)d_in[1];
  const float* bias = (const float*)d_in[2];
  float* out = (float*)d_out;

  // workspace layout: [0,4): amax bits | [4096, 4096+1MB): Wt | [2MB, 2MB+32MB): sigT (+16KB read slack)
  uint_t*   amax = (uint_t*)d_ws;
  ushort_t* wt   = (ushort_t*)((char*)d_ws + 4096);
  ushort_t* sigT = (ushort_t*)((char*)d_ws + (size_t)(2u << 20));

  hipMemsetAsync(d_ws, 0, 4, stream);
  hipLaunchKernelGGL(k_absmax, dim3(256), dim3(256), 0, stream, w, amax, COUT * CIN * KW);
  hipLaunchKernelGGL(k_wprep, dim3(COUT, CIN), dim3(KW), 0, stream, w, (const float*)amax, wt);
  hipLaunchKernelGGL(k_sprep, dim3(LSIG / 64, BATCH), dim3(256), 0, stream, sig, sigT);
  hipLaunchKernelGGL(k_conv, dim3((LOUT + NTILE - 1) / NTILE, BATCH), dim3(256), 0, stream,
                     sigT, wt, (const float*)amax, bias, out);
}

// Round 9
// 257.623 us; speedup vs baseline: 2.0054x; 1.1486x over previous
//
#include <hip/hip_runtime.h>

typedef unsigned short ushort_t;
typedef unsigned int   uint_t;

using bf16x8 = __attribute__((ext_vector_type(8))) short;
using f32x16 = __attribute__((ext_vector_type(16))) float;

#define BATCH 16
#define CIN   64
#define COUT  64
#define LSIG  16384
#define KW    128
#define LOUT  (LSIG - KW + 1)   /* 16257 */

#define NTILE 512                /* output positions per block */
#define ROWS  640                /* NTILE + 127 halo, rounded to 16 */

__device__ __forceinline__ ushort_t f2bf(float f) {
  union { float f; uint_t u; } v; v.f = f;
  uint_t r = v.u + 0x7fffu + ((v.u >> 16) & 1u);   // RNE, matches jnp f32->bf16
  return (ushort_t)(r >> 16);
}

// ---------------- pass 1: max|w| ----------------
__global__ void k_absmax(const float* __restrict__ w, uint_t* __restrict__ amax, int n) {
  int idx = blockIdx.x * blockDim.x + threadIdx.x;
  int stride = gridDim.x * blockDim.x;
  float m = 0.f;
  for (int i = idx; i < n; i += stride) m = fmaxf(m, fabsf(w[i]));
  for (int off = 32; off > 0; off >>= 1) m = fmaxf(m, __shfl_down(m, off, 64));
  if ((threadIdx.x & 63) == 0) atomicMax(amax, __float_as_uint(m)); // positive floats: uint order == float order
}

// ---------------- pass 2: quantize + reorder weights to FRAGMENT order ----------------
// wt2[((k*8 + frag)*64 + lane)*8 + j], frag = of*4+ks, lane = hi*32+l31,
// element (o,i) = (of*32+l31, ks*16+hi*8+j).  Each A-frag load in k_conv is then one
// fully-contiguous 1KB fetch (lane*16B), and all 8 waves/CU share the same L1 lines.
__global__ void k_wprep(const float* __restrict__ w, const float* __restrict__ amaxp,
                        ushort_t* __restrict__ wt2) {
  const float scale = amaxp[0] / 127.0f;
  const int o = blockIdx.x, i = blockIdx.y, k = threadIdx.x;
  const float q = rintf(w[((size_t)o * CIN + i) * KW + k] / scale); // integer in [-127,127], exact in bf16
  const int of = o >> 5, l31 = o & 31;
  const int ks = i >> 4, hi = (i >> 3) & 1, j = i & 7;
  const int frag = of * 4 + ks, lane = hi * 32 + l31;
  wt2[(((size_t)k * 8 + frag) * 64 + lane) * 8 + j] = f2bf(q);
}

// ---------------- pass 3: signal -> sigT[b][n][i] bf16, i-block XOR-swizzled by (n&7) ----------------
__global__ void k_sprep(const float* __restrict__ sig, ushort_t* __restrict__ sigT) {
  __shared__ float tile[64][65];
  const int b = blockIdx.y;
  const int n0 = blockIdx.x * 64;
  const int t = threadIdx.x;
  {
    const int i = t >> 2, q = t & 3;
    const float4* src = (const float4*)(sig + ((size_t)(b * CIN + i)) * LSIG + n0 + q * 16);
    float4 v0 = src[0], v1 = src[1], v2 = src[2], v3 = src[3];
    float* trow = &tile[i][q * 16];
    trow[0]=v0.x; trow[1]=v0.y; trow[2]=v0.z;  trow[3]=v0.w;
    trow[4]=v1.x; trow[5]=v1.y; trow[6]=v1.z;  trow[7]=v1.w;
    trow[8]=v2.x; trow[9]=v2.y; trow[10]=v2.z; trow[11]=v2.w;
    trow[12]=v3.x; trow[13]=v3.y; trow[14]=v3.z; trow[15]=v3.w;
  }
  __syncthreads();
  const int nl = t & 63, cg = t >> 6;
  const int n = n0 + nl;
  uint_t wds[8];
#pragma unroll
  for (int p = 0; p < 8; ++p) {
    const int c0 = cg * 16 + 2 * p;
    const int c1 = c0 + 1;
    const int ia = (((c0 >> 3) ^ (n & 7)) << 3) | (c0 & 7);
    const int ib = (((c1 >> 3) ^ (n & 7)) << 3) | (c1 & 7);
    wds[p] = (uint_t)f2bf(tile[ia][nl]) | ((uint_t)f2bf(tile[ib][nl]) << 16);
  }
  uint4* dst = (uint4*)(sigT + ((size_t)b * LSIG + n) * CIN + cg * 16);
  dst[0] = make_uint4(wds[0], wds[1], wds[2], wds[3]);
  dst[1] = make_uint4(wds[4], wds[5], wds[6], wds[7]);
}

// ---------------- pass 4: the conv (implicit GEMM, 32x32x16 MFMA) ----------------
// block: 256 threads = 4 waves; each wave owns 128 output positions x all 64 Cout.
// grid = 32 x 16 = 512 blocks = exactly 2 blocks/CU (2x80KB LDS = 160KB), 8 waves/CU.
// A = weights (fragment-ordered, contiguous 1KB/load), B = signal from LDS.
// Tap loop (128 taps): prefetch next tap's 8 A-frags (contiguous), sched_barrier pin,
// then 4 ks-steps of {4 ds_read_b128 (1 ahead) + setprio(1) 8 MFMA setprio(0)}.
#define KS_STEP(T, KS, A, BUSE, BLOAD, PFT, PFKS) do {                                 \
    { const int rbp_ = rowbase + (PFT);                                                \
      _Pragma("unroll") for (int nf = 0; nf < 4; ++nf) {                               \
        const int r_ = rbp_ + nf * 32;                                                 \
        BLOAD[nf] = *(const bf16x8*)((const char*)lds + r_ * 128 +                     \
                                     ((((PFKS) * 2 + hi) ^ (r_ & 7)) << 4));           \
      } }                                                                              \
    __builtin_amdgcn_s_setprio(1);                                                     \
    _Pragma("unroll") for (int of = 0; of < 2; ++of)                                   \
      _Pragma("unroll") for (int nf = 0; nf < 4; ++nf)                                 \
        acc[of][nf] = __builtin_amdgcn_mfma_f32_32x32x16_bf16(A[of * 4 + (KS)], BUSE[nf], acc[of][nf], 0, 0, 0); \
    __builtin_amdgcn_s_setprio(0);                                                     \
  } while (0)

#define TAP_BODY(T, ACUR, ANXT, DO_PF) do {                                            \
    if (DO_PF) {                                                                       \
      const ushort_t* pa_ = wa2 + (size_t)((T) + 1) * 4096;                            \
      _Pragma("unroll") for (int f = 0; f < 8; ++f)                                    \
        ANXT[f] = *(const bf16x8*)(pa_ + f * 512);                                     \
    }                                                                                  \
    __builtin_amdgcn_sched_barrier(0);                                                 \
    KS_STEP(T, 0, ACUR, B0, B1, (T), 1);                                               \
    KS_STEP(T, 1, ACUR, B1, B0, (T), 2);                                               \
    KS_STEP(T, 2, ACUR, B0, B1, (T), 3);                                               \
    KS_STEP(T, 3, ACUR, B1, B0, (T) + 1, 0);                                           \
  } while (0)

__global__ __launch_bounds__(256, 2) void k_conv(
    const ushort_t* __restrict__ sigT, const ushort_t* __restrict__ wt2,
    const float* __restrict__ amaxp, const float* __restrict__ bias,
    float* __restrict__ out)
{
  __shared__ __align__(16) ushort_t lds[ROWS * CIN];   // 80 KB
  const int b  = blockIdx.y;
  const int n0 = blockIdx.x * NTILE;
  const int t  = threadIdx.x;
  const int wv = t >> 6;
  const int lane = t & 63;
  const int l31 = lane & 31, hi = lane >> 5;

  // stage 640 rows x 128B = one contiguous 80KB span of sigT (clamped at buffer end;
  // overrun rows only feed store-masked outputs)
  {
    const uint4* srcall = (const uint4*)sigT;
    const size_t base = ((size_t)b * LSIG + n0) * 8;       // 8 uint4 per 128B row
    const size_t lim  = (size_t)BATCH * LSIG * 8;
    uint4* dst = (uint4*)lds;
    for (int c = t; c < ROWS * 8; c += 256) {
      size_t g = base + c;
      if (g >= lim) g = lim - 1;
      dst[c] = srcall[g];
    }
  }
  __syncthreads();

  f32x16 acc[2][4];
#pragma unroll
  for (int i = 0; i < 2; ++i)
#pragma unroll
    for (int j = 0; j < 4; ++j)
#pragma unroll
      for (int r = 0; r < 16; ++r) acc[i][j][r] = 0.f;

  // A: fragment-ordered layout; per-lane addr = tap*4096 + frag*512 + lane*8 (ushorts)
  const ushort_t* wa2 = wt2 + (size_t)lane * 8;
  const int rowbase = wv * 128 + l31;

  bf16x8 Aev[8], Aod[8], B0[4], B1[4];
  // prologue: full A for tap 0; B for (tap 0, ks 0)
#pragma unroll
  for (int f = 0; f < 8; ++f) Aev[f] = *(const bf16x8*)(wa2 + f * 512);
#pragma unroll
  for (int nf = 0; nf < 4; ++nf) {
    const int r_ = rowbase + nf * 32;
    B0[nf] = *(const bf16x8*)((const char*)lds + r_ * 128 + (((hi) ^ (r_ & 7)) << 4));
  }

  for (int tp = 0; tp < KW; tp += 2) {
    TAP_BODY(tp,     Aev, Aod, 1);
    TAP_BODY(tp + 1, Aod, Aev, (tp + 2 < KW));
  }

  const float sc = amaxp[0] / 127.0f;
#pragma unroll
  for (int of = 0; of < 2; ++of) {
#pragma unroll
    for (int nf = 0; nf < 4; ++nf) {
      const int n = n0 + wv * 128 + nf * 32 + l31;
      if (n < LOUT) {
#pragma unroll
        for (int r = 0; r < 16; ++r) {
          // D: col = lane&31 (= n), row o = of*32 + 4*hi + (r&3) + 8*(r>>2)  [m74/m101 layout]
          const int o = of * 32 + 4 * hi + (r & 3) + 8 * (r >> 2);
          out[((size_t)b * COUT + o) * LOUT + n] = acc[of][nf][r] * sc + bias[o];
        }
      }
    }
  }
}

extern "C" void kernel_launch(void* const* d_in, const int* in_sizes, int n_in,
                              void* d_out, int out_size, void* d_ws, size_t ws_size,
                              hipStream_t stream) {
  const float* sig  = (const float*)d_in[0];
  const float* w    = (const float*)d_in[1];
  const float* bias = (const float*)d_in[2];
  float* out = (float*)d_out;

  // workspace layout: [0,4): amax bits | [4096, 4096+1MB): wt2 | [2MB, 2MB+32MB): sigT (+16KB read slack)
  uint_t*   amax = (uint_t*)d_ws;
  ushort_t* wt2  = (ushort_t*)((char*)d_ws + 4096);
  ushort_t* sigT = (ushort_t*)((char*)d_ws + (size_t)(2u << 20));

  hipMemsetAsync(d_ws, 0, 4, stream);
  hipLaunchKernelGGL(k_absmax, dim3(256), dim3(256), 0, stream, w, amax, COUT * CIN * KW);
  hipLaunchKernelGGL(k_wprep, dim3(COUT, CIN), dim3(KW), 0, stream, w, (const float*)amax, wt2);
  hipLaunchKernelGGL(k_sprep, dim3(LSIG / 64, BATCH), dim3(256), 0, stream, sig, sigT);
  hipLaunchKernelGGL(k_conv, dim3((LOUT + NTILE - 1) / NTILE, BATCH), dim3(256), 0, stream,
                     sigT, wt2, (const float*)amax, bias, out);
}

// Round 10
// 254.197 us; speedup vs baseline: 2.0325x; 1.0135x over previous
//
#include <hip/hip_runtime.h>

typedef unsigned short ushort_t;
typedef unsigned int   uint_t;

using bf16x8 = __attribute__((ext_vector_type(8))) short;
using f32x16 = __attribute__((ext_vector_type(16))) float;

#define BATCH 16
#define CIN   64
#define COUT  64
#define LSIG  16384
#define KW    128
#define LOUT  (LSIG - KW + 1)   /* 16257 */

#define NTILE 512                /* output positions per block */
#define ROWS  640                /* NTILE + 127 halo, rounded to 16 */

__device__ __forceinline__ ushort_t f2bf(float f) {
  union { float f; uint_t u; } v; v.f = f;
  uint_t r = v.u + 0x7fffu + ((v.u >> 16) & 1u);   // RNE, matches jnp f32->bf16
  return (ushort_t)(r >> 16);
}

// ---------------- pass 1: max|w| ----------------
__global__ void k_absmax(const float* __restrict__ w, uint_t* __restrict__ amax, int n) {
  int idx = blockIdx.x * blockDim.x + threadIdx.x;
  int stride = gridDim.x * blockDim.x;
  float m = 0.f;
  for (int i = idx; i < n; i += stride) m = fmaxf(m, fabsf(w[i]));
  for (int off = 32; off > 0; off >>= 1) m = fmaxf(m, __shfl_down(m, off, 64));
  if ((threadIdx.x & 63) == 0) atomicMax(amax, __float_as_uint(m)); // positive floats: uint order == float order
}

// ---------------- pass 2: quantize + reorder weights to FRAGMENT order ----------------
// wt2[((k*8 + frag)*64 + lane)*8 + j], frag = of*4+ks, lane = hi*32+l31,
// element (o,i) = (of*32+l31, ks*16+hi*8+j).  Each A-frag load in k_conv is then one
// fully-contiguous 1KB fetch (lane*16B), and all 8 waves/CU share the same L1 lines.
__global__ void k_wprep(const float* __restrict__ w, const float* __restrict__ amaxp,
                        ushort_t* __restrict__ wt2) {
  const float scale = amaxp[0] / 127.0f;
  const int o = blockIdx.x, i = blockIdx.y, k = threadIdx.x;
  const float q = rintf(w[((size_t)o * CIN + i) * KW + k] / scale); // integer in [-127,127], exact in bf16
  const int of = o >> 5, l31 = o & 31;
  const int ks = i >> 4, hi = (i >> 3) & 1, j = i & 7;
  const int frag = of * 4 + ks, lane = hi * 32 + l31;
  wt2[(((size_t)k * 8 + frag) * 64 + lane) * 8 + j] = f2bf(q);
}

// ---------------- pass 3: signal -> sigT[b][n][i] bf16, i-block XOR-swizzled by (n&7) ----------------
__global__ void k_sprep(const float* __restrict__ sig, ushort_t* __restrict__ sigT) {
  __shared__ float tile[64][65];
  const int b = blockIdx.y;
  const int n0 = blockIdx.x * 64;
  const int t = threadIdx.x;
  {
    const int i = t >> 2, q = t & 3;
    const float4* src = (const float4*)(sig + ((size_t)(b * CIN + i)) * LSIG + n0 + q * 16);
    float4 v0 = src[0], v1 = src[1], v2 = src[2], v3 = src[3];
    float* trow = &tile[i][q * 16];
    trow[0]=v0.x; trow[1]=v0.y; trow[2]=v0.z;  trow[3]=v0.w;
    trow[4]=v1.x; trow[5]=v1.y; trow[6]=v1.z;  trow[7]=v1.w;
    trow[8]=v2.x; trow[9]=v2.y; trow[10]=v2.z; trow[11]=v2.w;
    trow[12]=v3.x; trow[13]=v3.y; trow[14]=v3.z; trow[15]=v3.w;
  }
  __syncthreads();
  const int nl = t & 63, cg = t >> 6;
  const int n = n0 + nl;
  uint_t wds[8];
#pragma unroll
  for (int p = 0; p < 8; ++p) {
    const int c0 = cg * 16 + 2 * p;
    const int c1 = c0 + 1;
    const int ia = (((c0 >> 3) ^ (n & 7)) << 3) | (c0 & 7);
    const int ib = (((c1 >> 3) ^ (n & 7)) << 3) | (c1 & 7);
    wds[p] = (uint_t)f2bf(tile[ia][nl]) | ((uint_t)f2bf(tile[ib][nl]) << 16);
  }
  uint4* dst = (uint4*)(sigT + ((size_t)b * LSIG + n) * CIN + cg * 16);
  dst[0] = make_uint4(wds[0], wds[1], wds[2], wds[3]);
  dst[1] = make_uint4(wds[4], wds[5], wds[6], wds[7]);
}

// ---------------- pass 4: the conv (implicit GEMM, 32x32x16 MFMA, uniform pipeline) ----------------
// block: 256 threads = 4 waves; each wave owns 128 output positions x all 64 Cout.
// grid = 32 x 16 = 512 blocks = exactly 2 blocks/CU (2x80KB LDS = 160KB), 8 waves/CU.
// A = weights (fragment-ordered, contiguous 1KB/load, single-buffered, reloaded
// fine-grained right after last use), B = signal from LDS, prefetch distance 2 steps
// (~516 cyc MFMA cover > LDS queue latency). Every ks-step is the identical bundle:
//   {4 ds_read_b128 for step s+2} SB {setprio(1) 8 MFMA setprio(0)} SB {2 A-loads for tap+1} SB
// so no per-tap load burst exists and waits are always counted, never immediate.
#define CONV_KS(KS) do {                                                               \
    { const int tpn_ = tp + (((KS) + 2) >> 2);                                         \
      const int kn_  = ((KS) + 2) & 3;                                                 \
      const int rb_  = rowbase + tpn_;                                                 \
      _Pragma("unroll") for (int nf = 0; nf < 4; ++nf) {                               \
        const int r_ = rb_ + nf * 32;                                                  \
        Bb[((KS) + 2) & 3][nf] = *(const bf16x8*)((const char*)lds + r_ * 128 +        \
                                   (((kn_ * 2 + hi) ^ (r_ & 7)) << 4));                \
      } }                                                                              \
    __builtin_amdgcn_sched_barrier(0);                                                 \
    __builtin_amdgcn_s_setprio(1);                                                     \
    _Pragma("unroll") for (int of = 0; of < 2; ++of)                                   \
      _Pragma("unroll") for (int nf = 0; nf < 4; ++nf)                                 \
        acc[of][nf] = __builtin_amdgcn_mfma_f32_32x32x16_bf16(A[of * 4 + (KS)], Bb[(KS)][nf], acc[of][nf], 0, 0, 0); \
    __builtin_amdgcn_s_setprio(0);                                                     \
    __builtin_amdgcn_sched_barrier(0);                                                 \
    { const ushort_t* pa_ = wa2 + (size_t)(tp + 1) * 4096;                             \
      _Pragma("unroll") for (int of = 0; of < 2; ++of)                                 \
        A[of * 4 + (KS)] = *(const bf16x8*)(pa_ + (of * 4 + (KS)) * 512);              \
    }                                                                                  \
    __builtin_amdgcn_sched_barrier(0);                                                 \
  } while (0)

__global__ __launch_bounds__(256, 2) void k_conv(
    const ushort_t* __restrict__ sigT, const ushort_t* __restrict__ wt2,
    const float* __restrict__ amaxp, const float* __restrict__ bias,
    float* __restrict__ out)
{
  __shared__ __align__(16) ushort_t lds[ROWS * CIN];   // 80 KB
  const int b  = blockIdx.y;
  const int n0 = blockIdx.x * NTILE;
  const int t  = threadIdx.x;
  const int wv = t >> 6;
  const int lane = t & 63;
  const int l31 = lane & 31, hi = lane >> 5;

  // stage 640 rows x 128B = one contiguous 80KB span of sigT (clamped at buffer end;
  // overrun rows only feed store-masked outputs)
  {
    const uint4* srcall = (const uint4*)sigT;
    const size_t base = ((size_t)b * LSIG + n0) * 8;       // 8 uint4 per 128B row
    const size_t lim  = (size_t)BATCH * LSIG * 8;
    uint4* dst = (uint4*)lds;
    for (int c = t; c < ROWS * 8; c += 256) {
      size_t g = base + c;
      if (g >= lim) g = lim - 1;
      dst[c] = srcall[g];
    }
  }
  __syncthreads();

  f32x16 acc[2][4];
#pragma unroll
  for (int i = 0; i < 2; ++i)
#pragma unroll
    for (int j = 0; j < 4; ++j)
#pragma unroll
      for (int r = 0; r < 16; ++r) acc[i][j][r] = 0.f;

  // A: fragment-ordered layout; per-lane addr = tap*4096 + frag*512 + lane*8 (ushorts)
  const ushort_t* wa2 = wt2 + (size_t)lane * 8;
  const int rowbase = wv * 128 + l31;

  bf16x8 A[8], Bb[4][4];
  // prologue: full A for tap 0; B for steps 0 (tap0,ks0) and 1 (tap0,ks1)
#pragma unroll
  for (int f = 0; f < 8; ++f) A[f] = *(const bf16x8*)(wa2 + f * 512);
#pragma unroll
  for (int nf = 0; nf < 4; ++nf) {
    const int r_ = rowbase + nf * 32;
    Bb[0][nf] = *(const bf16x8*)((const char*)lds + r_ * 128 + (((0 + hi) ^ (r_ & 7)) << 4));
    Bb[1][nf] = *(const bf16x8*)((const char*)lds + r_ * 128 + (((2 + hi) ^ (r_ & 7)) << 4));
  }

  for (int tp = 0; tp < KW; ++tp) {
    CONV_KS(0);
    CONV_KS(1);
    CONV_KS(2);
    CONV_KS(3);
  }
  // note: at tp=127 the prefetches target tap 128 — B rows stay within the 640-row
  // LDS tile (max index 639) and A reads stay inside d_ws; both values are never used.

  const float sc = amaxp[0] / 127.0f;
#pragma unroll
  for (int of = 0; of < 2; ++of) {
#pragma unroll
    for (int nf = 0; nf < 4; ++nf) {
      const int n = n0 + wv * 128 + nf * 32 + l31;
      if (n < LOUT) {
#pragma unroll
        for (int r = 0; r < 16; ++r) {
          // D: col = lane&31 (= n), row o = of*32 + 4*hi + (r&3) + 8*(r>>2)  [m74/m101 layout]
          const int o = of * 32 + 4 * hi + (r & 3) + 8 * (r >> 2);
          out[((size_t)b * COUT + o) * LOUT + n] = acc[of][nf][r] * sc + bias[o];
        }
      }
    }
  }
}

extern "C" void kernel_launch(void* const* d_in, const int* in_sizes, int n_in,
                              void* d_out, int out_size, void* d_ws, size_t ws_size,
                              hipStream_t stream) {
  const float* sig  = (const float*)d_in[0];
  const float* w    = (const float*)d_in[1];
  const float* bias = (const float*)d_in[2];
  float* out = (float*)d_out;

  // workspace layout: [0,4): amax bits | [4096, 4096+1MB+8KB slack): wt2 | [2MB, 2MB+32MB): sigT
  uint_t*   amax = (uint_t*)d_ws;
  ushort_t* wt2  = (ushort_t*)((char*)d_ws + 4096);
  ushort_t* sigT = (ushort_t*)((char*)d_ws + (size_t)(2u << 20));

  hipMemsetAsync(d_ws, 0, 4, stream);
  hipLaunchKernelGGL(k_absmax, dim3(256), dim3(256), 0, stream, w, amax, COUT * CIN * KW);
  hipLaunchKernelGGL(k_wprep, dim3(COUT, CIN), dim3(KW), 0, stream, w, (const float*)amax, wt2);
  hipLaunchKernelGGL(k_sprep, dim3(LSIG / 64, BATCH), dim3(256), 0, stream, sig, sigT);
  hipLaunchKernelGGL(k_conv, dim3((LOUT + NTILE - 1) / NTILE, BATCH), dim3(256), 0, stream,
                     sigT, wt2, (const float*)amax, bias, out);
}